// Round 6
// baseline (400.682 us; speedup 1.0000x reference)
//
#include <hip/hip_runtime.h>

#define HIDDEN 128
#define N_RAYS 65536
#define NEAR_D 0.01f
#define FAR_D 10.0f
#define MAX_ITERS 32

typedef _Float16 f16x8 __attribute__((ext_vector_type(8)));
typedef float f32x16 __attribute__((ext_vector_type(16)));

// DPP-assisted add: v + (v shifted by CTRL). Immediates via template params.
// bound_ctrl=1 -> out-of-bounds source lanes contribute 0.
template <int CTRL, int ROW_MASK>
__device__ __forceinline__ float dpp_add(float v) {
    int s = __builtin_amdgcn_update_dpp(0, __float_as_int(v), CTRL, ROW_MASK, 0xF, true);
    return v + __int_as_float(s);
}
// Sum over each 32-lane half; result lands in lane 31 (half 0) / lane 63 (half 1).
__device__ __forceinline__ float half_sum_dpp(float v) {
    v = dpp_add<0x111, 0xF>(v);   // row_shr:1
    v = dpp_add<0x112, 0xF>(v);   // row_shr:2
    v = dpp_add<0x114, 0xF>(v);   // row_shr:4
    v = dpp_add<0x118, 0xF>(v);   // row_shr:8  -> lanes 15/31/47/63 hold 16-sums
    v = dpp_add<0x142, 0xA>(v);   // row_bcast15 -> lanes 31/63 hold 32-sums
    return v;
}

// ---------------------------------------------------------------------------
// Prologue: W2 B-operand fragment image (fp16 hi limb | lo limb).
//   img[l*16384 + (t*8+c)*512 + L*8 + j] == limb_l( W2[k][n] ),
//   n = t*32 + (L&31),  k = c*16 + ((L>>5)&1)*8 + j.
// ---------------------------------------------------------------------------
__global__ void w2_frag_kernel(const float* __restrict__ W2,
                               _Float16* __restrict__ img) {
    int tid = blockIdx.x * blockDim.x + threadIdx.x;   // 0..16383
    int j = tid & 7;
    int L = (tid >> 3) & 63;
    int tc = tid >> 9;
    int t = tc >> 3, c = tc & 7;
    int n = t * 32 + (L & 31);
    int k = c * 16 + ((L >> 5) & 1) * 8 + j;
    float w = W2[k * HIDDEN + n];
    _Float16 hi = (_Float16)w;
    _Float16 lo = (_Float16)(w - (float)hi);
    img[tid] = hi;
    img[16384 + tid] = lo;
}

// ---------------------------------------------------------------------------
// R16: N-SPLIT for occupancy. Diagnosis: per-SIMD util ~10% MFMA / ~17% VALU
// (counters are any-of-4-SIMD aggregated) at a hard 2 waves/SIMD cap
// (2048 waves / 1024 SIMDs) -> latency-bound; R12-R15 intra-wave scheduling
// changes were all neutral because there are too few waves to hide latency.
//   - 2 partner waves per 32-ray group; wave th=0 computes N-tiles {0,1},
//     th=1 computes {2,3}. ps-partials combine via LDS + barrier (t-sum is
//     linear in per-tile relu outputs). 4096 waves total.
//   - Only the HI-limb W2 image in LDS (32 KB); LO-limb B-frags read from
//     global (L2-resident 64 KB, coalesced, loop-invariant addresses,
//     prefetched one chunk ahead). LDS ~35 KB -> 4 blocks/CU.
//   - __launch_bounds__(256,4): 16 waves/CU = 4 waves/SIMD (2x latency hiding).
//   - Ray state duplicated across partner waves (deterministic lock-step).
//   - Block-wide exit via __syncthreads_and; frozen groups skip compute but
//     keep hitting both barriers.
// Per-acc MFMA chain order (Ah*Bh, Ah*Bl, Al*Bh) preserved; only the final
// fp32 t-sum re-associates (~1e-7 vs 2.4e-4 budget).
// ---------------------------------------------------------------------------
__launch_bounds__(256, 4)
__global__ void sphere_trace_kernel(
    const float* __restrict__ origins,
    const float* __restrict__ directions,
    const float* __restrict__ W1,    // [3][128]
    const float* __restrict__ b1,    // [128]
    const _Float16* __restrict__ w2img, // 32768 halfs (hi | lo)
    const float* __restrict__ b2,    // [128]
    const float* __restrict__ W3,    // [128]
    const float* __restrict__ b3,    // [1]
    const float* __restrict__ Wc1,   // [3][128]
    const float* __restrict__ bc1,   // [128]
    const float* __restrict__ Wc2,   // [128][3]
    const float* __restrict__ bc2,   // [3]
    float* __restrict__ out)         // [N][3]
{
    __shared__ __align__(16) _Float16 whi[16384];    // 32 KB hi-limb image
    __shared__ __align__(16) float4 w1s[128];        // 2 KB {W1x,W1y,W1z,b1}/k
    __shared__ float sbuf[2][2][32];                 // [group][thalf][ray]

    const int tid = threadIdx.x;
    const int lane = tid & 63;
    const int wv  = __builtin_amdgcn_readfirstlane(tid >> 6);  // 0..3
    const int grp = wv >> 1;           // ray group within block (0/1)
    const int th  = wv & 1;            // N-tile half (0 -> t{0,1}, 1 -> t{2,3})
    const int q = lane >> 5;           // half-wave id
    const int n32 = lane & 31;         // ray id within group / N-col in tile

    // ---- stage hi image (32 KB) + W1 pack into LDS
    {
        const float4* src = (const float4*)w2img;    // first 2048 float4 = hi
        float4* dst = (float4*)whi;
        #pragma unroll
        for (int i = 0; i < 8; ++i)
            dst[tid + 256 * i] = src[tid + 256 * i];
        if (tid < 128) {
            float4 wvv;
            wvv.x = W1[tid];
            wvv.y = W1[HIDDEN + tid];
            wvv.z = W1[2 * HIDDEN + tid];
            wvv.w = b1[tid];
            w1s[tid] = wvv;
        }
    }
    __syncthreads();

    // ---- analytic layer-1 magnitude bound constants (once per wave)
    float bAx, bAy, bAz, bB;
    {
        bAx = fmaxf(fabsf(W1[lane]),              fabsf(W1[lane + 64]));
        bAy = fmaxf(fabsf(W1[HIDDEN + lane]),     fabsf(W1[HIDDEN + lane + 64]));
        bAz = fmaxf(fabsf(W1[2 * HIDDEN + lane]), fabsf(W1[2 * HIDDEN + lane + 64]));
        bB  = fmaxf(fabsf(b1[lane]),              fabsf(b1[lane + 64]));
        #pragma unroll
        for (int m = 1; m < 64; m <<= 1) {
            bAx = fmaxf(bAx, __shfl_xor(bAx, m));
            bAy = fmaxf(bAy, __shfl_xor(bAy, m));
            bAz = fmaxf(bAz, __shfl_xor(bAz, m));
            bB  = fmaxf(bB,  __shfl_xor(bB,  m));
        }
    }

    // ---- ray state: ALL 64 lanes hold ray (lane&31)'s state; partner waves
    // hold identical duplicates (lock-step via deterministic FP)
    const int ray = blockIdx.x * 64 + grp * 32 + n32;
    float px = origins[ray * 3 + 0];
    float py = origins[ray * 3 + 1];
    float pz = origins[ray * 3 + 2];
    const float dx = directions[ray * 3 + 0];
    const float dy = directions[ray * 3 + 1];
    const float dz = directions[ray * 3 + 2];
    float dist = 0.0f;
    bool frozen = false;

    // ---- per-lane epilogue constants for this wave's 2 N-tiles
    const int t0 = th * 2;
    float b2v[2], w3v[2];
    #pragma unroll
    for (int tt = 0; tt < 2; ++tt) {
        b2v[tt] = b2[(t0 + tt) * 32 + n32];
        w3v[tt] = W3[(t0 + tt) * 32 + n32];
    }
    const float b3v = b3[0];
    const int q8 = q * 8;
    const int fb0 = t0 * 8;            // fragment-row base, tile t0
    const int fb1 = fb0 + 8;           // tile t0+1
    const _Float16* lo_base  = w2img + 16384 + (lane << 3);
    const _Float16* whi_lane = whi + (lane << 3);

    #pragma unroll 1
    for (int it = 0; it < MAX_ITERS; ++it) {
        const bool gdone = (__ballot(!frozen) == 0ull);   // wave-uniform
        if (!gdone) {
            const float ppx = px, ppy = py, ppz = pz;

            // ---- analytic pow2 scale (bound >= true max of h for this ray)
            const float bound = fmaf(fabsf(ppx), bAx, fmaf(fabsf(ppy), bAy,
                                fmaf(fabsf(ppz), bAz, bB)));
            float sc = 1.0f, inv = 1.0f;
            {
                const int e = (int)((__float_as_uint(bound) >> 23) & 255u);
                if (e > 137) {
                    const int sh = e - 137;
                    sc  = __uint_as_float((unsigned)(127 - sh) << 23);
                    inv = __uint_as_float((unsigned)(127 + sh) << 23);
                }
            }

            f32x16 acc0, acc1;
            #pragma unroll
            for (int r = 0; r < 16; ++r) { acc0[r] = 0.0f; acc1[r] = 0.0f; }

            // prefetch chunk 0 lo-limb frags from global (L2-resident)
            f16x8 Bl0 = *(const f16x8*)(lo_base + (fb0 << 9));
            f16x8 Bl1 = *(const f16x8*)(lo_base + (fb1 << 9));

            #pragma unroll 1
            for (int c = 0; c < 8; ++c) {
                const f16x8 bh0 = *(const f16x8*)(whi_lane + ((fb0 + c) << 9));
                const f16x8 bh1 = *(const f16x8*)(whi_lane + ((fb1 + c) << 9));
                f16x8 BlN0, BlN1;
                if (c < 7) {   // prefetch next chunk's lo frags
                    BlN0 = *(const f16x8*)(lo_base + ((fb0 + c + 1) << 9));
                    BlN1 = *(const f16x8*)(lo_base + ((fb1 + c + 1) << 9));
                }
                // layer 1 for this chunk's 8 k-values, fused f16 hi/lo split
                f16x8 Ah, Al;
                {
                    const int kb = c * 16 + q8;
                    #pragma unroll
                    for (int jj = 0; jj < 8; ++jj) {
                        const float4 wvv = w1s[kb + jj];
                        const float hv = fmaxf(
                            fmaf(ppx, wvv.x, fmaf(ppy, wvv.y,
                            fmaf(ppz, wvv.z, wvv.w))), 0.0f);
                        const float x = hv * sc;           // exact (pow2)
                        const _Float16 hi = (_Float16)x;
                        Ah[jj] = hi;
                        Al[jj] = (_Float16)(x - (float)hi);
                    }
                }
                // 6 MFMAs; per-acc chain order (h, l, Al*h) preserved
                __builtin_amdgcn_s_setprio(1);
                acc0 = __builtin_amdgcn_mfma_f32_32x32x16_f16(Ah, bh0, acc0, 0, 0, 0);
                acc1 = __builtin_amdgcn_mfma_f32_32x32x16_f16(Ah, bh1, acc1, 0, 0, 0);
                acc0 = __builtin_amdgcn_mfma_f32_32x32x16_f16(Ah, Bl0, acc0, 0, 0, 0);
                acc1 = __builtin_amdgcn_mfma_f32_32x32x16_f16(Ah, Bl1, acc1, 0, 0, 0);
                acc0 = __builtin_amdgcn_mfma_f32_32x32x16_f16(Al, bh0, acc0, 0, 0, 0);
                acc1 = __builtin_amdgcn_mfma_f32_32x32x16_f16(Al, bh1, acc1, 0, 0, 0);
                __builtin_amdgcn_s_setprio(0);
                if (c < 7) { Bl0 = BlN0; Bl1 = BlN1; }
            }

            // ---- epilogue: inverse scales via readlane (exact, no LDS)
            float invr[16];
            #pragma unroll
            for (int r = 0; r < 16; ++r) {
                const int m0 = (r & 3) + 8 * (r >> 2);
                const float ilo = __uint_as_float(
                    (unsigned)__builtin_amdgcn_readlane(__float_as_uint(inv), m0));
                const float ihi = __uint_as_float(
                    (unsigned)__builtin_amdgcn_readlane(__float_as_uint(inv), m0 + 4));
                invr[r] = q ? ihi : ilo;
            }
            float ps[16];
            #pragma unroll
            for (int r = 0; r < 16; ++r) {
                const float v0 = fmaxf(fmaf(acc0[r], invr[r], b2v[0]), 0.0f);
                const float v1 = fmaxf(fmaf(acc1[r], invr[r], b2v[1]), 0.0f);
                ps[r] = fmaf(v1, w3v[1], v0 * w3v[0]);
            }

            // ---- 32-lane DPP reduction; sums land in lanes 31/63
            #pragma unroll
            for (int r = 0; r < 16; ++r)
                ps[r] = half_sum_dpp(ps[r]);
            if ((lane & 31) == 31) {
                const int mb = q * 4;
                #pragma unroll
                for (int g = 0; g < 4; ++g) {
                    float4 v4;
                    v4.x = ps[4 * g + 0];
                    v4.y = ps[4 * g + 1];
                    v4.z = ps[4 * g + 2];
                    v4.w = ps[4 * g + 3];
                    *(float4*)&sbuf[grp][th][8 * g + mb] = v4;
                }
            }
        }
        __syncthreads();                       // partials visible block-wide
        if (!gdone) {
            // combine partner t-halves; identical adds in both partner waves
            const float s = sbuf[grp][0][n32] + sbuf[grp][1][n32] + b3v;
            const bool valid = (s <= NEAR_D) && (dist < FAR_D);
            if (!frozen) {
                if (valid) {
                    frozen = true;
                } else {
                    dist += s;
                    px = fmaf(dx, s, px);
                    py = fmaf(dy, s, py);
                    pz = fmaf(dz, s, pz);
                }
            }
        }
        // doubles as the write-protect barrier for sbuf
        if (__syncthreads_and((int)frozen)) break;
    }

    // ---- color MLP (once), th==0 waves only: lane owns units lane, lane+64
    if (th == 0) {
        const int k0 = lane, k1 = lane + 64;
        const float cx0 = Wc1[k0], cx1 = Wc1[k1];
        const float cy0 = Wc1[HIDDEN + k0], cy1 = Wc1[HIDDEN + k1];
        const float cz0 = Wc1[2 * HIDDEN + k0], cz1 = Wc1[2 * HIDDEN + k1];
        const float cb0 = bc1[k0], cb1 = bc1[k1];
        const float u00 = Wc2[k0 * 3 + 0], u01 = Wc2[k0 * 3 + 1], u02 = Wc2[k0 * 3 + 2];
        const float u10 = Wc2[k1 * 3 + 0], u11 = Wc2[k1 * 3 + 1], u12 = Wc2[k1 * 3 + 2];

        float g0 = 0.f, g1 = 0.f, g2 = 0.f;
        #pragma unroll 1
        for (int m = 0; m < 32; ++m) {
            const float qx = __shfl(px, m);
            const float qy = __shfl(py, m);
            const float qz = __shfl(pz, m);
            const float h0 = fmaxf(fmaf(qx, cx0, fmaf(qy, cy0, fmaf(qz, cz0, cb0))), 0.f);
            const float h1 = fmaxf(fmaf(qx, cx1, fmaf(qy, cy1, fmaf(qz, cz1, cb1))), 0.f);
            float a0 = fmaf(h0, u00, h1 * u10);
            float a1 = fmaf(h0, u01, h1 * u11);
            float a2 = fmaf(h0, u02, h1 * u12);
            #pragma unroll
            for (int mask = 1; mask < 64; mask <<= 1) {
                a0 += __shfl_xor(a0, mask);
                a1 += __shfl_xor(a1, mask);
                a2 += __shfl_xor(a2, mask);
            }
            if (lane == m) { g0 = a0; g1 = a1; g2 = a2; }
        }

        if (lane < 32) {
            float c0 = 0.f, c1 = 0.f, c2 = 0.f;
            if (frozen || dist < FAR_D) {
                c0 = 1.0f / (1.0f + __expf(-(g0 + bc2[0])));
                c1 = 1.0f / (1.0f + __expf(-(g1 + bc2[1])));
                c2 = 1.0f / (1.0f + __expf(-(g2 + bc2[2])));
            }
            out[ray * 3 + 0] = c0;
            out[ray * 3 + 1] = c1;
            out[ray * 3 + 2] = c2;
        }
    }
}

extern "C" void kernel_launch(void* const* d_in, const int* in_sizes, int n_in,
                              void* d_out, int out_size, void* d_ws, size_t ws_size,
                              hipStream_t stream) {
    const float* origins    = (const float*)d_in[0];
    const float* directions = (const float*)d_in[1];
    const float* W1  = (const float*)d_in[2];
    const float* b1  = (const float*)d_in[3];
    const float* W2  = (const float*)d_in[4];
    const float* b2  = (const float*)d_in[5];
    const float* W3  = (const float*)d_in[6];
    const float* b3  = (const float*)d_in[7];
    const float* Wc1 = (const float*)d_in[8];
    const float* bc1 = (const float*)d_in[9];
    const float* Wc2 = (const float*)d_in[10];
    const float* bc2 = (const float*)d_in[11];
    float* out = (float*)d_out;

    _Float16* w2img = (_Float16*)d_ws;   // 64 KB fragment image (hi | lo)

    w2_frag_kernel<<<64, 256, 0, stream>>>(W2, w2img);

    sphere_trace_kernel<<<N_RAYS / 64, 256, 0, stream>>>(
        origins, directions, W1, b1, w2img, b2, W3, b3,
        Wc1, bc1, Wc2, bc2, out);
}

// Round 7
// 349.992 us; speedup vs baseline: 1.1448x; 1.1448x over previous
//
#include <hip/hip_runtime.h>

#define HIDDEN 128
#define N_RAYS 65536
#define NEAR_D 0.01f
#define FAR_D 10.0f
#define MAX_ITERS 32

typedef _Float16 f16x8 __attribute__((ext_vector_type(8)));
typedef float f32x4 __attribute__((ext_vector_type(4)));

// DPP-assisted add: v + (v shifted by CTRL).
template <int CTRL, int ROW_MASK>
__device__ __forceinline__ float dpp_add(float v) {
    int s = __builtin_amdgcn_update_dpp(0, __float_as_int(v), CTRL, ROW_MASK, 0xF, true);
    return v + __int_as_float(s);
}
// Sum within each 16-lane row; lane 15 of each row holds the row's 16-sum.
__device__ __forceinline__ float row16_sum_dpp(float v) {
    v = dpp_add<0x111, 0xF>(v);   // row_shr:1
    v = dpp_add<0x112, 0xF>(v);   // row_shr:2
    v = dpp_add<0x114, 0xF>(v);   // row_shr:4
    v = dpp_add<0x118, 0xF>(v);   // row_shr:8
    return v;
}

// ---------------------------------------------------------------------------
// Prologue: W2 B-operand fragment image for 16x16x32 MFMA (fp16 hi | lo limb).
//   img[limb*16384 + (t*4 + c)*512 + L*8 + j] == limb( W2[k][n] ),
//   n = t*16 + (L&15),  k = c*32 + ((L>>4)&3)*8 + j.
//   (t = N-tile 0..7, c = K-chunk 0..3, L = lane, j = elem)
// ---------------------------------------------------------------------------
__global__ void w2_frag_kernel(const float* __restrict__ W2,
                               _Float16* __restrict__ img) {
    int tid = blockIdx.x * blockDim.x + threadIdx.x;   // 0..16383
    int j = tid & 7;
    int L = (tid >> 3) & 63;
    int tc = tid >> 9;                 // 0..31
    int t = tc >> 2, c = tc & 3;
    int n = t * 16 + (L & 15);
    int k = c * 32 + ((L >> 4) & 3) * 8 + j;
    float w = W2[k * HIDDEN + n];
    _Float16 hi = (_Float16)w;
    _Float16 lo = (_Float16)(w - (float)hi);
    img[tid] = hi;
    img[16384 + tid] = lo;
}

// ---------------------------------------------------------------------------
// R17: 16-ray waves via mfma_f32_16x16x32_f16 to BREAK THE WAVE-COUNT CAP.
// Diagnosis recap: at 32 rays/wave the chip holds only 2048 waves = 2/SIMD;
// ~70% of SIMD cycles are exposed-latency stalls (R13 counters), intra-wave
// scheduling was neutral (R12-R15), and R16's wave-split failed because of
// duplicated layer-1 + per-iter barriers lockstepping waves.
// This version: 16 rays/wave -> 4096 FULLY INDEPENDENT waves (no barriers in
// the march loop, no duplicated work; each wave owns layer1+MFMA+epilogue for
// its rays). 4 blocks/CU (LDS ~34 KB) x 4 waves = 4 waves/SIMD.
//   - hi-limb W2 image in LDS (32 KB, 16x16 frag layout); lo-limb frags
//     stream from global (32 KB, L1-resident, coalesced b128).
//   - ray state held by ALL lanes for ray (lane&15) (4x duplicate, lock-step).
//   - A-frag: row=lane&15 (ray), k=c*32+(lane>>4)*8+j  (verified-analog map).
//   - C: col=lane&15 (n), row=(lane>>4)*4+reg (m89-verified) -> reduction is
//     4 DPP chains x 4 steps within 16-lane rows (cheaper than 32x32 path).
//   - per-acc limb order (Ah*Bh, Ah*Bl, Al*Bh) preserved; t-chains spaced 4.
// ---------------------------------------------------------------------------
__launch_bounds__(256, 4)
__global__ void sphere_trace_kernel(
    const float* __restrict__ origins,
    const float* __restrict__ directions,
    const float* __restrict__ W1,    // [3][128]
    const float* __restrict__ b1,    // [128]
    const _Float16* __restrict__ w2img, // 32768 halfs (hi | lo), 16x16 layout
    const float* __restrict__ b2,    // [128]
    const float* __restrict__ W3,    // [128]
    const float* __restrict__ b3,    // [1]
    const float* __restrict__ Wc1,   // [3][128]
    const float* __restrict__ bc1,   // [128]
    const float* __restrict__ Wc2,   // [128][3]
    const float* __restrict__ bc2,   // [3]
    float* __restrict__ out)         // [N][3]
{
    __shared__ __align__(16) _Float16 whi[16384];    // 32 KB hi-limb image
    __shared__ __align__(16) float sbuf[4][16];      // per-wave s exchange

    const int tid = threadIdx.x;
    const int lane = tid & 63;
    const int wv = __builtin_amdgcn_readfirstlane(tid >> 6);  // 0..3
    const int r16 = lane & 15;         // ray id in wave / C col
    const int g4 = lane >> 4;          // k-group / C row group (0..3)

    // ---- stage hi-limb image into LDS (only block-wide barrier here)
    {
        const float4* src = (const float4*)w2img;    // first 2048 float4 = hi
        float4* dst = (float4*)whi;
        #pragma unroll
        for (int i = 0; i < 8; ++i)
            dst[tid + 256 * i] = src[tid + 256 * i];
    }
    __syncthreads();

    // ---- analytic layer-1 magnitude bound constants (once per wave)
    float bAx, bAy, bAz, bB;
    {
        bAx = fmaxf(fabsf(W1[lane]),              fabsf(W1[lane + 64]));
        bAy = fmaxf(fabsf(W1[HIDDEN + lane]),     fabsf(W1[HIDDEN + lane + 64]));
        bAz = fmaxf(fabsf(W1[2 * HIDDEN + lane]), fabsf(W1[2 * HIDDEN + lane + 64]));
        bB  = fmaxf(fabsf(b1[lane]),              fabsf(b1[lane + 64]));
        #pragma unroll
        for (int m = 1; m < 64; m <<= 1) {
            bAx = fmaxf(bAx, __shfl_xor(bAx, m));
            bAy = fmaxf(bAy, __shfl_xor(bAy, m));
            bAz = fmaxf(bAz, __shfl_xor(bAz, m));
            bB  = fmaxf(bB,  __shfl_xor(bB,  m));
        }
    }

    // ---- ray state: all 64 lanes hold ray (lane&15)'s state (4x duplicate)
    const int ray = blockIdx.x * 64 + wv * 16 + r16;
    float px = origins[ray * 3 + 0];
    float py = origins[ray * 3 + 1];
    float pz = origins[ray * 3 + 2];
    const float dx = directions[ray * 3 + 0];
    const float dy = directions[ray * 3 + 1];
    const float dz = directions[ray * 3 + 2];
    float dist = 0.0f;
    bool frozen = false;

    // ---- per-lane epilogue constants (8 output columns n = t*16 + r16)
    float b2v[8], w3v[8];
    #pragma unroll
    for (int t = 0; t < 8; ++t) {
        b2v[t] = b2[t * 16 + r16];
        w3v[t] = W3[t * 16 + r16];
    }
    const float b3v = b3[0];
    const int koff8 = g4 * 8;
    const _Float16* hi_lane = whi + (lane << 3);
    const _Float16* lo_lane = w2img + 16384 + (lane << 3);
    float* sw = &sbuf[wv][0];

    #pragma unroll 1
    for (int it = 0; it < MAX_ITERS; ++it) {
        const float ppx = px, ppy = py, ppz = pz;

        // ---- analytic pow2 scale (bound >= true max of h for this ray)
        const float bound = fmaf(fabsf(ppx), bAx, fmaf(fabsf(ppy), bAy,
                            fmaf(fabsf(ppz), bAz, bB)));
        float sc = 1.0f, inv = 1.0f;
        {
            const int e = (int)((__float_as_uint(bound) >> 23) & 255u);
            if (e > 137) {
                const int sh = e - 137;
                sc  = __uint_as_float((unsigned)(127 - sh) << 23);
                inv = __uint_as_float((unsigned)(127 + sh) << 23);
            }
        }

        f32x4 acc[8];
        #pragma unroll
        for (int t = 0; t < 8; ++t)
            #pragma unroll
            for (int r = 0; r < 4; ++r) acc[t][r] = 0.0f;

        #pragma unroll 1
        for (int c = 0; c < 4; ++c) {
            // layer 1: 8 k-values for this lane's (ray, k-slice), hi/lo split
            f16x8 Ah, Al;
            {
                const int kb = c * 32 + koff8;
                #pragma unroll
                for (int jj = 0; jj < 8; ++jj) {
                    const float wx = W1[kb + jj];
                    const float wy = W1[HIDDEN + kb + jj];
                    const float wz = W1[2 * HIDDEN + kb + jj];
                    const float bb = b1[kb + jj];
                    const float hv = fmaxf(
                        fmaf(ppx, wx, fmaf(ppy, wy, fmaf(ppz, wz, bb))), 0.0f);
                    const float x = hv * sc;               // exact (pow2)
                    const _Float16 hi = (_Float16)x;
                    Ah[jj] = hi;
                    Al[jj] = (_Float16)(x - (float)hi);
                }
            }
            const int cb = c << 9;     // chunk offset (halfs); tile stride 2048

            // ---- quad A: tiles 0..3
            {
                const f16x8 bh0 = *(const f16x8*)(hi_lane + cb);
                const f16x8 bh1 = *(const f16x8*)(hi_lane + cb + 2048);
                const f16x8 bh2 = *(const f16x8*)(hi_lane + cb + 4096);
                const f16x8 bh3 = *(const f16x8*)(hi_lane + cb + 6144);
                const f16x8 bl0 = *(const f16x8*)(lo_lane + cb);
                const f16x8 bl1 = *(const f16x8*)(lo_lane + cb + 2048);
                const f16x8 bl2 = *(const f16x8*)(lo_lane + cb + 4096);
                const f16x8 bl3 = *(const f16x8*)(lo_lane + cb + 6144);
                __builtin_amdgcn_s_setprio(1);
                acc[0] = __builtin_amdgcn_mfma_f32_16x16x32_f16(Ah, bh0, acc[0], 0, 0, 0);
                acc[1] = __builtin_amdgcn_mfma_f32_16x16x32_f16(Ah, bh1, acc[1], 0, 0, 0);
                acc[2] = __builtin_amdgcn_mfma_f32_16x16x32_f16(Ah, bh2, acc[2], 0, 0, 0);
                acc[3] = __builtin_amdgcn_mfma_f32_16x16x32_f16(Ah, bh3, acc[3], 0, 0, 0);
                acc[0] = __builtin_amdgcn_mfma_f32_16x16x32_f16(Ah, bl0, acc[0], 0, 0, 0);
                acc[1] = __builtin_amdgcn_mfma_f32_16x16x32_f16(Ah, bl1, acc[1], 0, 0, 0);
                acc[2] = __builtin_amdgcn_mfma_f32_16x16x32_f16(Ah, bl2, acc[2], 0, 0, 0);
                acc[3] = __builtin_amdgcn_mfma_f32_16x16x32_f16(Ah, bl3, acc[3], 0, 0, 0);
                acc[0] = __builtin_amdgcn_mfma_f32_16x16x32_f16(Al, bh0, acc[0], 0, 0, 0);
                acc[1] = __builtin_amdgcn_mfma_f32_16x16x32_f16(Al, bh1, acc[1], 0, 0, 0);
                acc[2] = __builtin_amdgcn_mfma_f32_16x16x32_f16(Al, bh2, acc[2], 0, 0, 0);
                acc[3] = __builtin_amdgcn_mfma_f32_16x16x32_f16(Al, bh3, acc[3], 0, 0, 0);
                __builtin_amdgcn_s_setprio(0);
            }
            // ---- quad B: tiles 4..7
            {
                const f16x8 bh4 = *(const f16x8*)(hi_lane + cb + 8192);
                const f16x8 bh5 = *(const f16x8*)(hi_lane + cb + 10240);
                const f16x8 bh6 = *(const f16x8*)(hi_lane + cb + 12288);
                const f16x8 bh7 = *(const f16x8*)(hi_lane + cb + 14336);
                const f16x8 bl4 = *(const f16x8*)(lo_lane + cb + 8192);
                const f16x8 bl5 = *(const f16x8*)(lo_lane + cb + 10240);
                const f16x8 bl6 = *(const f16x8*)(lo_lane + cb + 12288);
                const f16x8 bl7 = *(const f16x8*)(lo_lane + cb + 14336);
                __builtin_amdgcn_s_setprio(1);
                acc[4] = __builtin_amdgcn_mfma_f32_16x16x32_f16(Ah, bh4, acc[4], 0, 0, 0);
                acc[5] = __builtin_amdgcn_mfma_f32_16x16x32_f16(Ah, bh5, acc[5], 0, 0, 0);
                acc[6] = __builtin_amdgcn_mfma_f32_16x16x32_f16(Ah, bh6, acc[6], 0, 0, 0);
                acc[7] = __builtin_amdgcn_mfma_f32_16x16x32_f16(Ah, bh7, acc[7], 0, 0, 0);
                acc[4] = __builtin_amdgcn_mfma_f32_16x16x32_f16(Ah, bl4, acc[4], 0, 0, 0);
                acc[5] = __builtin_amdgcn_mfma_f32_16x16x32_f16(Ah, bl5, acc[5], 0, 0, 0);
                acc[6] = __builtin_amdgcn_mfma_f32_16x16x32_f16(Ah, bl6, acc[6], 0, 0, 0);
                acc[7] = __builtin_amdgcn_mfma_f32_16x16x32_f16(Ah, bl7, acc[7], 0, 0, 0);
                acc[4] = __builtin_amdgcn_mfma_f32_16x16x32_f16(Al, bh4, acc[4], 0, 0, 0);
                acc[5] = __builtin_amdgcn_mfma_f32_16x16x32_f16(Al, bh5, acc[5], 0, 0, 0);
                acc[6] = __builtin_amdgcn_mfma_f32_16x16x32_f16(Al, bh6, acc[6], 0, 0, 0);
                acc[7] = __builtin_amdgcn_mfma_f32_16x16x32_f16(Al, bh7, acc[7], 0, 0, 0);
                __builtin_amdgcn_s_setprio(0);
            }
        }

        // ---- epilogue: C row = g4*4 + r (= ray); fetch that ray's inv
        float invr[4];
        #pragma unroll
        for (int r = 0; r < 4; ++r)
            invr[r] = __shfl(inv, 4 * g4 + r);   // src lanes 0..15 hold rays

        float ps[4];
        #pragma unroll
        for (int r = 0; r < 4; ++r) ps[r] = 0.0f;
        #pragma unroll
        for (int t = 0; t < 8; ++t) {
            #pragma unroll
            for (int r = 0; r < 4; ++r) {
                const float v = fmaxf(fmaf(acc[t][r], invr[r], b2v[t]), 0.0f);
                ps[r] = fmaf(v, w3v[t], ps[r]);
            }
        }

        // ---- 16-lane DPP reduction; row sums land in lanes 15/31/47/63
        #pragma unroll
        for (int r = 0; r < 4; ++r)
            ps[r] = row16_sum_dpp(ps[r]);
        if (r16 == 15) {
            float4 v4;
            v4.x = ps[0]; v4.y = ps[1]; v4.z = ps[2]; v4.w = ps[3];
            *(float4*)&sw[4 * g4] = v4;          // rays 4*g4 .. 4*g4+3
        }
        const float s = sw[r16] + b3v;           // same-wave LDS roundtrip

        // ---- march (exact reference semantics), duplicated across copies
        {
            const bool valid = (s <= NEAR_D) && (dist < FAR_D);
            if (!frozen) {
                if (valid) {
                    frozen = true;
                } else {
                    dist += s;
                    px = fmaf(dx, s, px);
                    py = fmaf(dy, s, py);
                    pz = fmaf(dz, s, pz);
                }
            }
        }
        if (__ballot(!frozen) == 0) break;       // per-wave independent exit
    }

    // ---- color MLP (once): lane owns hidden units lane, lane+64; 16 rays
    const int k0 = lane, k1 = lane + 64;
    const float cx0 = Wc1[k0], cx1 = Wc1[k1];
    const float cy0 = Wc1[HIDDEN + k0], cy1 = Wc1[HIDDEN + k1];
    const float cz0 = Wc1[2 * HIDDEN + k0], cz1 = Wc1[2 * HIDDEN + k1];
    const float cb0 = bc1[k0], cb1 = bc1[k1];
    const float u00 = Wc2[k0 * 3 + 0], u01 = Wc2[k0 * 3 + 1], u02 = Wc2[k0 * 3 + 2];
    const float u10 = Wc2[k1 * 3 + 0], u11 = Wc2[k1 * 3 + 1], u12 = Wc2[k1 * 3 + 2];

    float g0 = 0.f, g1 = 0.f, g2 = 0.f;
    #pragma unroll 1
    for (int m = 0; m < 16; ++m) {
        const float qx = __shfl(px, m);
        const float qy = __shfl(py, m);
        const float qz = __shfl(pz, m);
        const float h0 = fmaxf(fmaf(qx, cx0, fmaf(qy, cy0, fmaf(qz, cz0, cb0))), 0.f);
        const float h1 = fmaxf(fmaf(qx, cx1, fmaf(qy, cy1, fmaf(qz, cz1, cb1))), 0.f);
        float a0 = fmaf(h0, u00, h1 * u10);
        float a1 = fmaf(h0, u01, h1 * u11);
        float a2 = fmaf(h0, u02, h1 * u12);
        #pragma unroll
        for (int mask = 1; mask < 64; mask <<= 1) {
            a0 += __shfl_xor(a0, mask);
            a1 += __shfl_xor(a1, mask);
            a2 += __shfl_xor(a2, mask);
        }
        if (lane == m) { g0 = a0; g1 = a1; g2 = a2; }
    }

    if (lane < 16) {
        float c0 = 0.f, c1 = 0.f, c2 = 0.f;
        if (frozen || dist < FAR_D) {
            c0 = 1.0f / (1.0f + __expf(-(g0 + bc2[0])));
            c1 = 1.0f / (1.0f + __expf(-(g1 + bc2[1])));
            c2 = 1.0f / (1.0f + __expf(-(g2 + bc2[2])));
        }
        out[ray * 3 + 0] = c0;
        out[ray * 3 + 1] = c1;
        out[ray * 3 + 2] = c2;
    }
}

extern "C" void kernel_launch(void* const* d_in, const int* in_sizes, int n_in,
                              void* d_out, int out_size, void* d_ws, size_t ws_size,
                              hipStream_t stream) {
    const float* origins    = (const float*)d_in[0];
    const float* directions = (const float*)d_in[1];
    const float* W1  = (const float*)d_in[2];
    const float* b1  = (const float*)d_in[3];
    const float* W2  = (const float*)d_in[4];
    const float* b2  = (const float*)d_in[5];
    const float* W3  = (const float*)d_in[6];
    const float* b3  = (const float*)d_in[7];
    const float* Wc1 = (const float*)d_in[8];
    const float* bc1 = (const float*)d_in[9];
    const float* Wc2 = (const float*)d_in[10];
    const float* bc2 = (const float*)d_in[11];
    float* out = (float*)d_out;

    _Float16* w2img = (_Float16*)d_ws;   // 64 KB fragment image (hi | lo)

    w2_frag_kernel<<<64, 256, 0, stream>>>(W2, w2img);

    sphere_trace_kernel<<<N_RAYS / 64, 256, 0, stream>>>(
        origins, directions, W1, b1, w2img, b2, W3, b3,
        Wc1, bc1, Wc2, bc2, out);
}

// Round 9
// 292.786 us; speedup vs baseline: 1.3685x; 1.1954x over previous
//
#include <hip/hip_runtime.h>

#define HIDDEN 128
#define N_RAYS 65536
#define NEAR_D 0.01f
#define FAR_D 10.0f
#define MAX_ITERS 32

typedef _Float16 f16x8 __attribute__((ext_vector_type(8)));
typedef __fp16 fp16x2 __attribute__((ext_vector_type(2)));   // cvt_pkrtz result type
typedef float f32x16 __attribute__((ext_vector_type(16)));

// DPP-assisted add: v + (v shifted by CTRL).
template <int CTRL, int ROW_MASK>
__device__ __forceinline__ float dpp_add(float v) {
    int s = __builtin_amdgcn_update_dpp(0, __float_as_int(v), CTRL, ROW_MASK, 0xF, true);
    return v + __int_as_float(s);
}
// Sum over each 32-lane half; result lands in lane 31 (half 0) / lane 63 (half 1).
__device__ __forceinline__ float half_sum_dpp(float v) {
    v = dpp_add<0x111, 0xF>(v);   // row_shr:1
    v = dpp_add<0x112, 0xF>(v);   // row_shr:2
    v = dpp_add<0x114, 0xF>(v);   // row_shr:4
    v = dpp_add<0x118, 0xF>(v);   // row_shr:8  -> lanes 15/31/47/63 hold 16-sums
    v = dpp_add<0x142, 0xA>(v);   // row_bcast15 -> lanes 31/63 hold 32-sums
    return v;
}

// ---------------------------------------------------------------------------
// Prologue: W2 B-operand fragment image (fp16 hi limb | lo limb).
//   img[l*16384 + (t*8+c)*512 + L*8 + j] == limb_l( W2[k][n] ),
//   n = t*32 + (L&31),  k = c*16 + ((L>>5)&1)*8 + j.
// ---------------------------------------------------------------------------
__global__ void w2_frag_kernel(const float* __restrict__ W2,
                               _Float16* __restrict__ img) {
    int tid = blockIdx.x * blockDim.x + threadIdx.x;   // 0..16383
    int j = tid & 7;
    int L = (tid >> 3) & 63;
    int tc = tid >> 9;
    int t = tc >> 3, c = tc & 7;
    int n = t * 32 + (L & 31);
    int k = c * 16 + ((L >> 5) & 1) * 8 + j;
    float w = W2[k * HIDDEN + n];
    _Float16 hi = (_Float16)w;
    _Float16 lo = (_Float16)(w - (float)hi);
    img[tid] = hi;
    img[16384 + tid] = lo;
}

// ---------------------------------------------------------------------------
// R19 == R18 with the cvt_pkrtz type fixed (__fp16 vec2 -> union bit-reinterp).
// R18: VALU-work reduction on the R13/R15 structure (best so far, 273 us).
// Corrected HW model: mfma_32x32x16 = ~32 SIMD-cycles (2.5 PF peak / m119)
// -> R13 runs ~30% MFMA-pipe + ~50% VALU per SIMD: pipe-ISSUE-bound, not
// latency-bound. (Explains R16/R17: adding waves vs half-busy pipes lost.)
// So: remove VALU ops, keep structure.
//   (a) pow2-scaling apparatus DELETED (bound consts, exponent branch,
//       per-jj sc mul, invr readlane gather). hi/lo f16 limbs are
//       magnitude-independent; h <= ~300 while dist<FAR (f16 max 65504);
//       post-FAR runaway rays overflow->NaN but land in the
//       (dist<FAR)=false, frozen=false -> color-0 path = reference output.
//   (b) v_cvt_pkrtz packs 2 f16 conversions/instr for both limbs.
//   (c) b2 folded into acc init (acc = b2 + A*B), epilogue relu is 1 op.
//   (d) t-sequential MFMA order (R13's; R15's round-robin was -8us).
// ---------------------------------------------------------------------------
__launch_bounds__(256, 2)
__global__ void sphere_trace_kernel(
    const float* __restrict__ origins,
    const float* __restrict__ directions,
    const float* __restrict__ W1,    // [3][128]
    const float* __restrict__ b1,    // [128]
    const _Float16* __restrict__ w2img, // 32768 halfs (hi | lo)
    const float* __restrict__ b2,    // [128]
    const float* __restrict__ W3,    // [128]
    const float* __restrict__ b3,    // [1]
    const float* __restrict__ Wc1,   // [3][128]
    const float* __restrict__ bc1,   // [128]
    const float* __restrict__ Wc2,   // [128][3]
    const float* __restrict__ bc2,   // [3]
    float* __restrict__ out)         // [N][3]
{
    __shared__ __align__(16) _Float16 wlds[32768];   // 64 KB fragment image
    __shared__ __align__(16) float4 w1s[128];        // 2 KB: {W1x,W1y,W1z,b1}/k
    __shared__ float sbuf[4][32];                    // per-wave s exchange

    const int tid = threadIdx.x;
    const int lane = tid & 63;
    const int w = __builtin_amdgcn_readfirstlane(tid >> 6);
    const int q = lane >> 5;           // half-wave id
    const int n32 = lane & 31;         // N-column within tile / ray id

    // ---- stage fragment image + W1 pack into LDS (only __syncthreads here)
    {
        const float4* src = (const float4*)w2img;
        float4* dst = (float4*)wlds;
        #pragma unroll
        for (int i = 0; i < 16; ++i)
            dst[tid + 256 * i] = src[tid + 256 * i];
        if (tid < 128) {
            float4 wv;
            wv.x = W1[tid];
            wv.y = W1[HIDDEN + tid];
            wv.z = W1[2 * HIDDEN + tid];
            wv.w = b1[tid];
            w1s[tid] = wv;
        }
    }
    __syncthreads();

    // ---- ray state: ALL 64 lanes hold ray (lane&31)'s state (hi mirrors lo)
    const int ray = blockIdx.x * 128 + w * 32 + n32;
    float px = origins[ray * 3 + 0];
    float py = origins[ray * 3 + 1];
    float pz = origins[ray * 3 + 2];
    const float dx = directions[ray * 3 + 0];
    const float dy = directions[ray * 3 + 1];
    const float dz = directions[ray * 3 + 2];
    float dist = 0.0f;
    bool frozen = false;

    // ---- per-lane epilogue constants (4 output columns n = t*32 + n32)
    float b2v[4], w3v[4];
    #pragma unroll
    for (int t = 0; t < 4; ++t) {
        b2v[t] = b2[t * 32 + n32];
        w3v[t] = W3[t * 32 + n32];
    }
    const float b3v = b3[0];
    const int q8 = q * 8;

    #pragma unroll 1
    for (int it = 0; it < MAX_ITERS; ++it) {
        const float ppx = px, ppy = py, ppz = pz;

        // layer-1 for one 8-k group: unscaled, packed-f16 hi/lo limb split
        auto layer1 = [&](int kb, f16x8& Ah, f16x8& Al) {
            union { f16x8 v; fp16x2 p[4]; } uh, ul;
            #pragma unroll
            for (int jp = 0; jp < 4; ++jp) {
                const float4 w0 = w1s[kb + 2 * jp];
                const float4 w1v = w1s[kb + 2 * jp + 1];
                const float x0 = fmaxf(
                    fmaf(ppx, w0.x, fmaf(ppy, w0.y, fmaf(ppz, w0.z, w0.w))), 0.0f);
                const float x1 = fmaxf(
                    fmaf(ppx, w1v.x, fmaf(ppy, w1v.y, fmaf(ppz, w1v.z, w1v.w))), 0.0f);
                const fp16x2 hi = __builtin_amdgcn_cvt_pkrtz(x0, x1);
                const float l0 = x0 - (float)hi[0];
                const float l1 = x1 - (float)hi[1];
                uh.p[jp] = hi;
                ul.p[jp] = __builtin_amdgcn_cvt_pkrtz(l0, l1);
            }
            Ah = uh.v; Al = ul.v;
        };

        // ---- layer 2: chunk-outer loop, depth-1 pipeline on A-fragments.
        // acc starts at b2 (C = b2 + A*B).
        f32x16 acc[4];
        #pragma unroll
        for (int t = 0; t < 4; ++t)
            #pragma unroll
            for (int r = 0; r < 16; ++r) acc[t][r] = b2v[t];

        f16x8 Ah, Al, AhN, AlN;
        layer1(q8, Ah, Al);                   // chunk 0

        #pragma unroll 1
        for (int c = 0; c < 8; ++c) {
            // issue chunk c's B-frag ds_reads (named vars, static t indices)
            const int base = (c << 9) + (lane << 3);
            const f16x8 b0h = *(const f16x8*)(wlds + base);
            const f16x8 b0l = *(const f16x8*)(wlds + 16384 + base);
            const f16x8 b1h = *(const f16x8*)(wlds + base + (1 << 12));
            const f16x8 b1l = *(const f16x8*)(wlds + 16384 + base + (1 << 12));
            const f16x8 b2h = *(const f16x8*)(wlds + base + (2 << 12));
            const f16x8 b2l = *(const f16x8*)(wlds + 16384 + base + (2 << 12));
            const f16x8 b3h = *(const f16x8*)(wlds + base + (3 << 12));
            const f16x8 b3l = *(const f16x8*)(wlds + 16384 + base + (3 << 12));

            // chunk c+1 layer-1 VALU burst overlaps the ds_read latency
            if (c < 7) layer1((c + 1) * 16 + q8, AhN, AlN);

            // 12 MFMAs, t-sequential; per-acc order (Ah*Bh, Ah*Bl, Al*Bh)
            __builtin_amdgcn_s_setprio(1);
            acc[0] = __builtin_amdgcn_mfma_f32_32x32x16_f16(Ah, b0h, acc[0], 0, 0, 0);
            acc[0] = __builtin_amdgcn_mfma_f32_32x32x16_f16(Ah, b0l, acc[0], 0, 0, 0);
            acc[0] = __builtin_amdgcn_mfma_f32_32x32x16_f16(Al, b0h, acc[0], 0, 0, 0);
            acc[1] = __builtin_amdgcn_mfma_f32_32x32x16_f16(Ah, b1h, acc[1], 0, 0, 0);
            acc[1] = __builtin_amdgcn_mfma_f32_32x32x16_f16(Ah, b1l, acc[1], 0, 0, 0);
            acc[1] = __builtin_amdgcn_mfma_f32_32x32x16_f16(Al, b1h, acc[1], 0, 0, 0);
            acc[2] = __builtin_amdgcn_mfma_f32_32x32x16_f16(Ah, b2h, acc[2], 0, 0, 0);
            acc[2] = __builtin_amdgcn_mfma_f32_32x32x16_f16(Ah, b2l, acc[2], 0, 0, 0);
            acc[2] = __builtin_amdgcn_mfma_f32_32x32x16_f16(Al, b2h, acc[2], 0, 0, 0);
            acc[3] = __builtin_amdgcn_mfma_f32_32x32x16_f16(Ah, b3h, acc[3], 0, 0, 0);
            acc[3] = __builtin_amdgcn_mfma_f32_32x32x16_f16(Ah, b3l, acc[3], 0, 0, 0);
            acc[3] = __builtin_amdgcn_mfma_f32_32x32x16_f16(Al, b3h, acc[3], 0, 0, 0);
            __builtin_amdgcn_s_setprio(0);

            Ah = AhN; Al = AlN;
        }

        // ---- epilogue: relu (b2 already inside acc), dot W3
        float ps[16];
        #pragma unroll
        for (int r = 0; r < 16; ++r) ps[r] = 0.0f;
        #pragma unroll
        for (int t = 0; t < 4; ++t) {
            #pragma unroll
            for (int r = 0; r < 16; ++r) {
                const float v = fmaxf(acc[t][r], 0.0f);
                ps[r] = fmaf(v, w3v[t], ps[r]);
            }
        }

        // ---- 32-lane reduction on the VALU pipe (DPP); sums in lanes 31/63
        #pragma unroll
        for (int r = 0; r < 16; ++r)
            ps[r] = half_sum_dpp(ps[r]);
        if ((lane & 31) == 31) {
            const int mb = q * 4;      // q=0 -> rows 8g..8g+3; q=1 -> 8g+4..8g+7
            #pragma unroll
            for (int g = 0; g < 4; ++g) {
                float4 v4;
                v4.x = ps[4 * g + 0];
                v4.y = ps[4 * g + 1];
                v4.z = ps[4 * g + 2];
                v4.w = ps[4 * g + 3];
                *(float4*)&sbuf[w][8 * g + mb] = v4;
            }
        }
        // all lanes read their ray's s (hi lanes mirror lo lanes)
        const float s = sbuf[w][n32] + b3v;

        // ---- march (exact reference semantics), duplicated on both halves
        {
            const bool valid = (s <= NEAR_D) && (dist < FAR_D);
            if (!frozen) {
                if (valid) {
                    frozen = true;
                } else {
                    dist += s;
                    px = fmaf(dx, s, px);
                    py = fmaf(dy, s, py);
                    pz = fmaf(dz, s, pz);
                }
            }
        }
        if (__ballot((lane < 32) && !frozen) == 0) break;
    }

    // ---- color MLP (once): lane owns hidden units lane, lane+64
    const int k0 = lane, k1 = lane + 64;
    const float cx0 = Wc1[k0], cx1 = Wc1[k1];
    const float cy0 = Wc1[HIDDEN + k0], cy1 = Wc1[HIDDEN + k1];
    const float cz0 = Wc1[2 * HIDDEN + k0], cz1 = Wc1[2 * HIDDEN + k1];
    const float cb0 = bc1[k0], cb1 = bc1[k1];
    const float u00 = Wc2[k0 * 3 + 0], u01 = Wc2[k0 * 3 + 1], u02 = Wc2[k0 * 3 + 2];
    const float u10 = Wc2[k1 * 3 + 0], u11 = Wc2[k1 * 3 + 1], u12 = Wc2[k1 * 3 + 2];

    float g0 = 0.f, g1 = 0.f, g2 = 0.f;
    #pragma unroll 1
    for (int m = 0; m < 32; ++m) {
        const float qx = __shfl(px, m);
        const float qy = __shfl(py, m);
        const float qz = __shfl(pz, m);
        const float h0 = fmaxf(fmaf(qx, cx0, fmaf(qy, cy0, fmaf(qz, cz0, cb0))), 0.f);
        const float h1 = fmaxf(fmaf(qx, cx1, fmaf(qy, cy1, fmaf(qz, cz1, cb1))), 0.f);
        float a0 = fmaf(h0, u00, h1 * u10);
        float a1 = fmaf(h0, u01, h1 * u11);
        float a2 = fmaf(h0, u02, h1 * u12);
        #pragma unroll
        for (int mask = 1; mask < 64; mask <<= 1) {
            a0 += __shfl_xor(a0, mask);
            a1 += __shfl_xor(a1, mask);
            a2 += __shfl_xor(a2, mask);
        }
        if (lane == m) { g0 = a0; g1 = a1; g2 = a2; }
    }

    if (lane < 32) {
        float c0 = 0.f, c1 = 0.f, c2 = 0.f;
        if (frozen || dist < FAR_D) {
            c0 = 1.0f / (1.0f + __expf(-(g0 + bc2[0])));
            c1 = 1.0f / (1.0f + __expf(-(g1 + bc2[1])));
            c2 = 1.0f / (1.0f + __expf(-(g2 + bc2[2])));
        }
        out[ray * 3 + 0] = c0;
        out[ray * 3 + 1] = c1;
        out[ray * 3 + 2] = c2;
    }
}

extern "C" void kernel_launch(void* const* d_in, const int* in_sizes, int n_in,
                              void* d_out, int out_size, void* d_ws, size_t ws_size,
                              hipStream_t stream) {
    const float* origins    = (const float*)d_in[0];
    const float* directions = (const float*)d_in[1];
    const float* W1  = (const float*)d_in[2];
    const float* b1  = (const float*)d_in[3];
    const float* W2  = (const float*)d_in[4];
    const float* b2  = (const float*)d_in[5];
    const float* W3  = (const float*)d_in[6];
    const float* b3  = (const float*)d_in[7];
    const float* Wc1 = (const float*)d_in[8];
    const float* bc1 = (const float*)d_in[9];
    const float* Wc2 = (const float*)d_in[10];
    const float* bc2 = (const float*)d_in[11];
    float* out = (float*)d_out;

    _Float16* w2img = (_Float16*)d_ws;   // 64 KB fragment image

    w2_frag_kernel<<<64, 256, 0, stream>>>(W2, w2img);

    sphere_trace_kernel<<<N_RAYS / 128, 256, 0, stream>>>(
        origins, directions, W1, b1, w2img, b2, W3, b3,
        Wc1, bc1, Wc2, bc2, out);
}